// Round 3
// baseline (318.813 us; speedup 1.0000x reference)
//
#include <hip/hip_runtime.h>
#include <math.h>

#define H 1024
#define Nn 1024
#define Bb 64
#define Tt 256
#define BT (Bb * Tt)   // 16384

typedef unsigned short ushort_t;
typedef __attribute__((ext_vector_type(8))) short bf16x8;
typedef __attribute__((ext_vector_type(4))) float f32x4;

// ---------------- helpers ----------------

__device__ __forceinline__ ushort_t f2bf(float x) {
    union { float f; unsigned u; } v; v.f = x;
    unsigned r = v.u + 0x7FFFu + ((v.u >> 16) & 1u);   // RNE
    return (ushort_t)(r >> 16);
}
__device__ __forceinline__ float bf2f(ushort_t h) {
    union { unsigned u; float f; } v; v.u = ((unsigned)h) << 16; return v.f;
}

__device__ __forceinline__ float block_reduce_sum_256(float v) {
    __shared__ float sbuf[4];
    __syncthreads();
    #pragma unroll
    for (int off = 32; off > 0; off >>= 1) v += __shfl_down(v, off, 64);
    int lane = threadIdx.x & 63, w = threadIdx.x >> 6;
    if (lane == 0) sbuf[w] = v;
    __syncthreads();
    if (threadIdx.x == 0) sbuf[0] = sbuf[0] + sbuf[1] + sbuf[2] + sbuf[3];
    __syncthreads();
    return sbuf[0];
}

// ---------------- stage 1: hgate partials (t-split x8) + bf16 ht + seeds + weight prep ----
// grid 5120 x 256:
//  [0,2048):    b = id>>5, z = (id&31)>>2 (t-chunk of 32), cb = id&3.
//  [2048,3072): n2h_W^T hi/lo bf16 transpose tiles
//  [3072,4096): h2n_W flat hi/lo split
//  [4096,4608): W1T fp32
//  [4608,5120): W2T fp32
__global__ void k_stage1(const float* __restrict__ h_time, float* __restrict__ hg_part,
                         ushort_t* __restrict__ ht_bf16, const float* __restrict__ n2h_b,
                         float* __restrict__ rowsumS, float* __restrict__ bias_h,
                         const float* __restrict__ n2h_W, const float* __restrict__ h2n_W,
                         const float* __restrict__ W1, const float* __restrict__ W2,
                         ushort_t* __restrict__ n2hWT_h, ushort_t* __restrict__ n2hWT_l,
                         ushort_t* __restrict__ h2nW_h, ushort_t* __restrict__ h2nW_l,
                         float* __restrict__ W1T, float* __restrict__ W2T) {
    __shared__ float tile[32][33];
    int id = blockIdx.x;
    if (id < 2048) {
        int b = id >> 5, r = id & 31;
        int z = r >> 2, cb = r & 3;
        int col = cb * 256 + threadIdx.x;
        if (b == 0 && z == 0) {        // seed atomic accumulators (ws re-poisoned every call)
            rowsumS[col] = 0.f;
            bias_h[col] = n2h_b[col];
        }
        float s = 0.f;
        #pragma unroll 4
        for (int t = z * 32; t < z * 32 + 32; ++t) {
            size_t o = ((size_t)b * Tt + t) * H + col;
            float v = h_time[o];
            s += v;
            ht_bf16[o] = f2bf(v);
        }
        hg_part[(size_t)(b * 8 + z) * H + col] = s;
        return;
    }
    int tx = threadIdx.x & 31, ty = threadIdx.x >> 5;
    if (id < 3072) {            // n2h_W transpose + split
        int t = id - 2048;
        int i0 = (t >> 5) * 32, j0 = (t & 31) * 32;
        #pragma unroll
        for (int q = 0; q < 4; ++q)
            tile[ty + 8 * q][tx] = n2h_W[(size_t)(i0 + ty + 8 * q) * H + j0 + tx];
        __syncthreads();
        #pragma unroll
        for (int q = 0; q < 4; ++q) {
            float v = tile[tx][ty + 8 * q];
            size_t o = (size_t)(j0 + ty + 8 * q) * Nn + i0 + tx;
            ushort_t hh = f2bf(v);
            n2hWT_h[o] = hh;
            n2hWT_l[o] = f2bf(v - bf2f(hh));
        }
    } else if (id < 4096) {     // h2n_W flat split
        size_t idx = (size_t)(id - 3072) * 1024 + threadIdx.x * 4;
        float4 v = *(const float4*)&h2n_W[idx];
        float c[4] = {v.x, v.y, v.z, v.w};
        union { ushort_t u[4]; uint2 w; } ph, pl;
        #pragma unroll
        for (int q = 0; q < 4; ++q) {
            ph.u[q] = f2bf(c[q]);
            pl.u[q] = f2bf(c[q] - bf2f(ph.u[q]));
        }
        *(uint2*)&h2nW_h[idx] = ph.w;
        *(uint2*)&h2nW_l[idx] = pl.w;
    } else if (id < 4608) {     // W1T (W1 is 1024x512)
        int t = id - 4096;
        int i0 = (t >> 4) * 32, j0 = (t & 15) * 32;
        #pragma unroll
        for (int q = 0; q < 4; ++q)
            tile[ty + 8 * q][tx] = W1[(size_t)(i0 + ty + 8 * q) * 512 + j0 + tx];
        __syncthreads();
        #pragma unroll
        for (int q = 0; q < 4; ++q)
            W1T[(size_t)(j0 + ty + 8 * q) * 1024 + i0 + tx] = tile[tx][ty + 8 * q];
    } else {                    // W2T (W2 is 512x1024)
        int t = id - 4608;
        int i0 = (t >> 5) * 32, j0 = (t & 31) * 32;
        #pragma unroll
        for (int q = 0; q < 4; ++q)
            tile[ty + 8 * q][tx] = W2[(size_t)(i0 + ty + 8 * q) * 1024 + j0 + tx];
        __syncthreads();
        #pragma unroll
        for (int q = 0; q < 4; ++q)
            W2T[(size_t)(j0 + ty + 8 * q) * 512 + i0 + tx] = tile[tx][ty + 8 * q];
    }
}

// ---------------- stage 2: h_gate + h_mean from partials.  grid 260 x 256 ----------------
__global__ void k_stage2(const float* __restrict__ hg_part, float* __restrict__ h_gate,
                         float* __restrict__ h_mean) {
    int id = blockIdx.x;
    if (id < 256) {
        int b = id >> 2, cb = id & 3;
        int col = cb * 256 + threadIdx.x;
        float s = 0.f;
        #pragma unroll
        for (int z = 0; z < 8; ++z) s += hg_part[(size_t)(b * 8 + z) * H + col];
        h_gate[b * H + col] = s * (1.0f / Tt);
    } else {
        int h = (id - 256) * 256 + threadIdx.x;
        float s = 0.f;
        for (int r = 0; r < 512; ++r) s += hg_part[(size_t)r * H + h];
        h_mean[h] = s * (1.0f / (Bb * Tt));
    }
}

// ---------------- stage 3: E_cur bf16 + MLP layer 1.  grid 9216 x 256 --------------------
__global__ __launch_bounds__(256) void k_stage3(
    const float* __restrict__ E_dyn, const float* __restrict__ h_mean,
    ushort_t* __restrict__ E_b,
    const float* __restrict__ h_gate, const float* __restrict__ W1T,
    const float* __restrict__ b1, float* __restrict__ hid) {
    if (blockIdx.x < 1024) {   // E_b[n,:] = bf16(normalize(E_dyn[n,:] + h_mean))
        int n = blockIdx.x;
        float e[4]; float ss = 0.f;
        #pragma unroll
        for (int q = 0; q < 4; ++q) {
            int h = threadIdx.x + 256 * q;
            e[q] = E_dyn[(size_t)n * H + h] + h_mean[h];
            ss += e[q] * e[q];
        }
        float tot = block_reduce_sum_256(ss);
        float scale = 1.0f / fmaxf(sqrtf(tot), 1e-12f);
        #pragma unroll
        for (int q = 0; q < 4; ++q) {
            int h = threadIdx.x + 256 * q;
            E_b[(size_t)n * H + h] = f2bf(e[q] * scale);
        }
        return;
    }
    // hid[b][j] = gelu(dot(h_gate[b,:], W1T[j,:]) + b1[j]); wave per output
    int gid = (blockIdx.x - 1024) * 4 + (threadIdx.x >> 6);
    int lane = threadIdx.x & 63;
    int b = gid >> 9, j = gid & 511;
    const float* xr = h_gate + b * H;
    const float* wr = W1T + (size_t)j * H;
    float s = 0.f;
    #pragma unroll
    for (int it = 0; it < 4; ++it) {
        int k = it * 256 + lane * 4;
        float4 x4 = *(const float4*)&xr[k];
        float4 w4 = *(const float4*)&wr[k];
        s += x4.x * w4.x + x4.y * w4.y + x4.z * w4.z + x4.w * w4.w;
    }
    #pragma unroll
    for (int off = 32; off > 0; off >>= 1) s += __shfl_down(s, off, 64);
    if (lane == 0) {
        float a = s + b1[j];
        hid[b * 512 + j] = 0.5f * a * (1.0f + erff(a * 0.70710678118654752f));
    }
}

// ---------------- 64x64-tile MFMA GEMM body, BK=64, T2 swizzle + 2-phase pipeline --------
// C_raw = A@Bt^T (PASSES=1) or Ah@Bh^T + Ah@Bl^T + Al@Bh^T (PASSES=3).
// EPI 1: relu -> O1 bf16 + atomicAdd row-sums into fout.      (S = relu(E E^T))
// EPI 2: hi/lo bf16 -> O1,O2 + atomicAdd dot(row,fvec)->fout. (C1T + fused bias_h gemv)
// EPI 3: bf16 -> O1.                                          (C2t)
template <int PASSES, int EPI>
__device__ __forceinline__ void gemm64_body(
    int bx, int by,
    const ushort_t* __restrict__ Ah, const ushort_t* __restrict__ Al,
    const ushort_t* __restrict__ Bh, const ushort_t* __restrict__ Bl,
    ushort_t* __restrict__ O1, ushort_t* __restrict__ O2,
    float* __restrict__ fout, const float* __restrict__ fvec,
    int M, int N, int K) {
    constexpr int NST = (PASSES == 3) ? 4 : 2;
    constexpr int BUFSZ = NST * 64 * 64;
    __shared__ ushort_t sStage[2 * BUFSZ];   // double-buffered: 64 KB (3-pass) / 32 KB
    const int tid = threadIdx.x, wave = tid >> 6, lane = tid & 63;
    const int quad = lane >> 4, l16 = lane & 15;
    const int m0 = by * 64, n0 = bx * 64;
    const int wm = (wave >> 1) * 32, wn = (wave & 1) * 32;
    const int sw = (l16 & 7) << 3;   // read-side swizzle (row&7)<<3 in ushort units

    f32x4 acc[2][2];
    #pragma unroll
    for (int i = 0; i < 2; ++i)
        #pragma unroll
        for (int j = 0; j < 2; ++j)
            acc[i][j] = (f32x4){0.f, 0.f, 0.f, 0.f};

    auto stage = [&](int buf, int k0) {
        ushort_t* sAh = sStage + buf * BUFSZ;
        ushort_t* sBh = sAh + 64 * 64;
        ushort_t* sAl = sAh + 2 * 64 * 64;   // only used when PASSES==3
        ushort_t* sBl = sAh + 3 * 64 * 64;
        #pragma unroll
        for (int inst = 0; inst < 2; ++inst) {
            const int cbase = (wave * 2 + inst) * 64;
            const int c = cbase + lane;
            const int row = c >> 3;
            const int q = (c & 7) ^ (row & 7);   // inverse-swizzled source chunk
            const size_t offA = (size_t)(m0 + row) * K + k0 + q * 8;
            const size_t offB = (size_t)(n0 + row) * K + k0 + q * 8;
            __builtin_amdgcn_global_load_lds(
                (const __attribute__((address_space(1))) unsigned int*)(Ah + offA),
                (__attribute__((address_space(3))) unsigned int*)&sAh[cbase * 8], 16, 0, 0);
            __builtin_amdgcn_global_load_lds(
                (const __attribute__((address_space(1))) unsigned int*)(Bh + offB),
                (__attribute__((address_space(3))) unsigned int*)&sBh[cbase * 8], 16, 0, 0);
            if constexpr (PASSES == 3) {
                __builtin_amdgcn_global_load_lds(
                    (const __attribute__((address_space(1))) unsigned int*)(Al + offA),
                    (__attribute__((address_space(3))) unsigned int*)&sAl[cbase * 8], 16, 0, 0);
                __builtin_amdgcn_global_load_lds(
                    (const __attribute__((address_space(1))) unsigned int*)(Bl + offB),
                    (__attribute__((address_space(3))) unsigned int*)&sBl[cbase * 8], 16, 0, 0);
            }
        }
    };

    auto compute = [&](int buf) {
        const ushort_t* sAh = sStage + buf * BUFSZ;
        const ushort_t* sBh = sAh + 64 * 64;
        const ushort_t* sAl = sAh + 2 * 64 * 64;
        const ushort_t* sBl = sAh + 3 * 64 * 64;
        #pragma unroll
        for (int half = 0; half < 2; ++half) {
            bf16x8 fah[2], fbh[2];
            bf16x8 fal[PASSES == 3 ? 2 : 1], fbl[PASSES == 3 ? 2 : 1];
            #pragma unroll
            for (int i = 0; i < 2; ++i) {
                const int ko = ((half * 4 + quad) << 3) ^ sw;   // swizzled 16B chunk
                fah[i] = *(const bf16x8*)&sAh[(wm + i * 16 + l16) * 64 + ko];
                fbh[i] = *(const bf16x8*)&sBh[(wn + i * 16 + l16) * 64 + ko];
                if constexpr (PASSES == 3) {
                    fal[i] = *(const bf16x8*)&sAl[(wm + i * 16 + l16) * 64 + ko];
                    fbl[i] = *(const bf16x8*)&sBl[(wn + i * 16 + l16) * 64 + ko];
                }
            }
            #pragma unroll
            for (int i = 0; i < 2; ++i)
                #pragma unroll
                for (int j = 0; j < 2; ++j) {
                    acc[i][j] = __builtin_amdgcn_mfma_f32_16x16x32_bf16(fah[i], fbh[j], acc[i][j], 0, 0, 0);
                    if constexpr (PASSES == 3) {
                        acc[i][j] = __builtin_amdgcn_mfma_f32_16x16x32_bf16(fah[i], fbl[j], acc[i][j], 0, 0, 0);
                        acc[i][j] = __builtin_amdgcn_mfma_f32_16x16x32_bf16(fal[i], fbh[j], acc[i][j], 0, 0, 0);
                    }
                }
        }
    };

    // 2-phase pipelined K-loop
    stage(0, 0);
    __syncthreads();
    int cur = 0;
    for (int k0 = 64; k0 < K; k0 += 64) {
        stage(cur ^ 1, k0);   // next tile in flight across the compute
        compute(cur);
        __syncthreads();      // drains vmcnt(0): next buffer ready; reads done
        cur ^= 1;
    }
    compute(cur);

    // direct-from-register epilogue (outputs small/L2-resident; no LDS round-trip)
    float fv[2];
    if constexpr (EPI == 2) {
        #pragma unroll
        for (int j = 0; j < 2; ++j) fv[j] = fvec[n0 + wn + j * 16 + l16];
    }
    #pragma unroll
    for (int i = 0; i < 2; ++i)
        #pragma unroll
        for (int r = 0; r < 4; ++r) {
            const int m = m0 + wm + i * 16 + quad * 4 + r;
            float rowacc = 0.f;
            #pragma unroll
            for (int j = 0; j < 2; ++j) {
                const size_t o = (size_t)m * N + n0 + wn + j * 16 + l16;
                float v = acc[i][j][r];
                if constexpr (EPI == 1) {
                    v = fmaxf(v, 0.f);
                    O1[o] = f2bf(v);
                    rowacc += v;
                } else if constexpr (EPI == 2) {
                    ushort_t hh = f2bf(v);
                    O1[o] = hh;
                    O2[o] = f2bf(v - bf2f(hh));
                    rowacc += v * fv[j];
                } else {
                    O1[o] = f2bf(v);
                }
            }
            if constexpr (EPI == 1 || EPI == 2) {
                rowacc += __shfl_xor(rowacc, 1);
                rowacc += __shfl_xor(rowacc, 2);
                rowacc += __shfl_xor(rowacc, 4);
                rowacc += __shfl_xor(rowacc, 8);
                if (l16 == 0) atomicAdd(&fout[m], rowacc);
            }
        }
}

// ---------------- stage 4: MLP layer 2 (gmean) + S-GEMM.  grid 512 x 256 -----------------
__global__ __launch_bounds__(256) void k_stage4(
    const float* __restrict__ hid, const float* __restrict__ W2T,
    const float* __restrict__ b2, float* __restrict__ gmean,
    const ushort_t* __restrict__ E_b, ushort_t* __restrict__ Sb,
    float* __restrict__ rowsumS) {
    if (blockIdx.x < 256) {
        int n = blockIdx.x * 4 + (threadIdx.x >> 6);
        int lane = threadIdx.x & 63;
        const float* wr = W2T + (size_t)n * 512;
        float4 w0 = *(const float4*)&wr[lane * 4];
        float4 w1 = *(const float4*)&wr[256 + lane * 4];
        float bb = b2[n];
        float acc = 0.f;
        for (int b = 0; b < Bb; ++b) {
            const float* xr = hid + b * 512;
            float4 x0 = *(const float4*)&xr[lane * 4];
            float4 x1 = *(const float4*)&xr[256 + lane * 4];
            float s = x0.x * w0.x + x0.y * w0.y + x0.z * w0.z + x0.w * w0.w
                    + x1.x * w1.x + x1.y * w1.y + x1.z * w1.z + x1.w * w1.w;
            #pragma unroll
            for (int off = 32; off > 0; off >>= 1) s += __shfl_down(s, off, 64);
            if (lane == 0) acc += 1.0f / (1.0f + expf(-(s + bb)));
        }
        if (lane == 0) gmean[n] = acc * (1.0f / Bb);
        return;
    }
    int t = blockIdx.x - 256;
    gemm64_body<1, 1>(t & 15, t >> 4, E_b, nullptr, E_b, nullptr,
                      Sb, nullptr, rowsumS, nullptr, Nn, Nn, H);
}

// ---------------- A_mix transposed + hi/lo split.  grid(32,32) x 256 ---------------------
__global__ void k_amixT(const ushort_t* __restrict__ Sb, const float* __restrict__ A_p,
                        const float* __restrict__ rowsumS, const float* __restrict__ gmean,
                        const float* __restrict__ alpha_raw,
                        ushort_t* __restrict__ Th, ushort_t* __restrict__ Tl) {
    __shared__ float tile[32][33];
    int i0 = blockIdx.y * 32, j0 = blockIdx.x * 32;
    int tx = threadIdx.x & 31, ty = threadIdx.x >> 5;
    float alpha = 1.0f / (1.0f + expf(-alpha_raw[0]));
    #pragma unroll
    for (int q = 0; q < 4; ++q) {
        int i = i0 + ty + 8 * q, j = j0 + tx;
        size_t idx = (size_t)i * Nn + j;
        float s = bf2f(Sb[idx]);
        float ad = 0.5f * s * (1.0f / (rowsumS[i] + 1e-6f) + 1.0f / (rowsumS[j] + 1e-6f));
        tile[ty + 8 * q][tx] = gmean[i] * fmaf(alpha, A_p[idx], (1.0f - alpha) * ad);
    }
    __syncthreads();
    #pragma unroll
    for (int q = 0; q < 4; ++q) {
        float v = tile[tx][ty + 8 * q];
        size_t o = (size_t)(j0 + ty + 8 * q) * Nn + i0 + tx;
        ushort_t hh = f2bf(v);
        Th[o] = hh;
        Tl[o] = f2bf(v - bf2f(hh));
    }
}

// chain GEMM wrappers.  grid 256 x 256
__global__ __launch_bounds__(256) void k_c1t(
    const ushort_t* __restrict__ Ah, const ushort_t* __restrict__ Al,
    const ushort_t* __restrict__ Bh, const ushort_t* __restrict__ Bl,
    ushort_t* __restrict__ O1, ushort_t* __restrict__ O2,
    float* __restrict__ fout, const float* __restrict__ fvec) {
    gemm64_body<3, 2>(blockIdx.x & 15, blockIdx.x >> 4, Ah, Al, Bh, Bl, O1, O2, fout, fvec,
                      Nn, Nn, Nn);
}
__global__ __launch_bounds__(256) void k_c2t(
    const ushort_t* __restrict__ Ah, const ushort_t* __restrict__ Al,
    const ushort_t* __restrict__ Bh, const ushort_t* __restrict__ Bl,
    ushort_t* __restrict__ O1) {
    gemm64_body<3, 3>(blockIdx.x & 15, blockIdx.x >> 4, Ah, Al, Bh, Bl, O1, nullptr,
                      nullptr, nullptr, Nn, Nn, Nn);
}

// ---------------- 256x256 MFMA GEMM, BK=64, 8 waves, phase-split schedule ----------------
// y[m][n] = (ht @ C2t^T)[m][n] + bias[n] + SC*bf16(ht[m][n]), fp32 -> fout.
// Structure (T2+T3+T5): per K-tile 4 phases {ds_read quadrant | (phase0: stage ALL of
// next tile) -> raw s_barrier -> lgkmcnt(0) -> setprio(1) 16 MFMA setprio(0) -> raw
// s_barrier}.  The ONLY vmcnt drain is the per-tile __syncthreads(), at which point the
// outstanding loads are the ones issued 4 phases earlier (counted-vmcnt property achieved
// structurally: fresh loads are issued AFTER the drain point, never drained).
// Intra-tile raw barriers touch a read-only buffer -> compiler reorder across them is
// correctness-harmless; the __syncthreads() full fence protects the buffer swap.
// Grid 256 (64 m-tiles x 4 n-tiles): bid&3 = n-tile, so each XCD sees one 512 KB B-panel.
__global__ __launch_bounds__(512, 2) void gemm_big(
    const ushort_t* __restrict__ A, const ushort_t* __restrict__ Bt,
    float* __restrict__ fout, const float* __restrict__ fvec,
    int M, int N, int K) {
    constexpr int BUFSZ = 2 * 256 * 64;              // per-buffer ushorts (A+B)
    __shared__ ushort_t sStage[2 * BUFSZ];           // 128 KB

    const int tid = threadIdx.x;
    const int wave = tid >> 6, lane = tid & 63;
    const int quad = lane >> 4, l16 = lane & 15;
    const int wr = wave >> 2, wc = wave & 3;         // 2 x 4 wave grid
    const int m0 = (blockIdx.x >> 2) * 256;
    const int n0 = (blockIdx.x & 3) * 256;
    const int wm = wr * 128, wn = wc * 64;           // per-wave 128 x 64 output
    const int swz = l16 & 7;

    f32x4 acc[8][4];
    #pragma unroll
    for (int i = 0; i < 8; ++i)
        #pragma unroll
        for (int j = 0; j < 4; ++j)
            acc[i][j] = (f32x4){0.f, 0.f, 0.f, 0.f};

    auto stage = [&](int buf, int k0) {
        ushort_t* sA = sStage + buf * BUFSZ;
        ushort_t* sB = sA + 256 * 64;
        #pragma unroll
        for (int pass = 0; pass < 4; ++pass) {
            const int c = pass * 512 + tid;
            const int row = c >> 3;
            const int q = (c & 7) ^ (row & 7);   // inverse-swizzled source chunk
            const size_t offA = (size_t)(m0 + row) * K + k0 + q * 8;
            const size_t offB = (size_t)(n0 + row) * K + k0 + q * 8;
            __builtin_amdgcn_global_load_lds(
                (const __attribute__((address_space(1))) unsigned int*)(A + offA),
                (__attribute__((address_space(3))) unsigned int*)&sA[c * 8], 16, 0, 0);
            __builtin_amdgcn_global_load_lds(
                (const __attribute__((address_space(1))) unsigned int*)(Bt + offB),
                (__attribute__((address_space(3))) unsigned int*)&sB[c * 8], 16, 0, 0);
        }
    };

    stage(0, 0);
    int buf = 0;
    for (int t = 0; t < 16; ++t) {
        __syncthreads();   // drain: only tile t's loads outstanding (issued 4 phases ago)
        if (t + 1 < 16) stage(buf ^ 1, (t + 1) * 64);
        const ushort_t* sA = sStage + buf * BUFSZ;
        const ushort_t* sB = sA + 256 * 64;
        #pragma unroll
        for (int s = 0; s < 2; ++s) {          // K-half
            bf16x8 fb[4];
            #pragma unroll
            for (int j = 0; j < 4; ++j) {
                const int row = wn + j * 16 + l16;
                const int ch = (s * 4 + quad) ^ swz;
                fb[j] = *(const bf16x8*)&sB[row * 64 + ch * 8];
            }
            #pragma unroll
            for (int mh = 0; mh < 2; ++mh) {   // M-half of the wave's 128 rows
                bf16x8 fa[4];
                #pragma unroll
                for (int i = 0; i < 4; ++i) {
                    const int row = wm + mh * 64 + i * 16 + l16;
                    const int ch = (s * 4 + quad) ^ swz;
                    fa[i] = *(const bf16x8*)&sA[row * 64 + ch * 8];
                }
                __builtin_amdgcn_s_barrier();
                asm volatile("s_waitcnt lgkmcnt(0)" ::: "memory");
                __builtin_amdgcn_sched_barrier(0);
                __builtin_amdgcn_s_setprio(1);
                #pragma unroll
                for (int i = 0; i < 4; ++i)
                    #pragma unroll
                    for (int j = 0; j < 4; ++j)
                        acc[mh * 4 + i][j] =
                            __builtin_amdgcn_mfma_f32_16x16x32_bf16(fa[i], fb[j], acc[mh * 4 + i][j], 0, 0, 0);
                __builtin_amdgcn_s_setprio(0);
                __builtin_amdgcn_s_barrier();
            }
        }
        buf ^= 1;
    }
    __syncthreads();   // staging dead; epilogue overlays the full 128 KB

    // Epilogue: per-wave LDS transpose (16 KB/wave = 4 m-frags per pass, 2 passes) ->
    // coalesced float4 IO.  __syncthreads between write/read: type-punned LDS (R4 lesson).
    float* Es = (float*)sStage + wave * 4096;
    const float SC = 1.0009765622f;   // 1 + tanh(1/1024): attention branch is this constant

    #pragma unroll
    for (int pass = 0; pass < 2; ++pass) {
        #pragma unroll
        for (int ii = 0; ii < 4; ++ii) {
            const int i = pass * 4 + ii;
            #pragma unroll
            for (int j = 0; j < 4; ++j)
                #pragma unroll
                for (int r = 0; r < 4; ++r)
                    Es[ii * 1024 + (quad * 4 + r) * 64 + j * 16 + l16] = acc[i][j][r];
        }
        __syncthreads();
        #pragma unroll
        for (int ii = 0; ii < 4; ++ii) {
            #pragma unroll
            for (int it = 0; it < 4; ++it) {
                const int idx = it * 64 + lane;
                const int row = idx >> 4, f4 = idx & 15;
                const int m = m0 + wm + (pass * 4 + ii) * 16 + row;
                const int coln = n0 + wn + f4 * 4;
                float4 v = *(const float4*)&Es[ii * 1024 + row * 64 + f4 * 4];
                float4 b4 = *(const float4*)&fvec[coln];
                ushort4 h4 = *(const ushort4*)&A[(size_t)m * N + coln];
                float4 y;
                y.x = v.x + b4.x + SC * bf2f(h4.x);
                y.y = v.y + b4.y + SC * bf2f(h4.y);
                y.z = v.z + b4.z + SC * bf2f(h4.z);
                y.w = v.w + b4.w + SC * bf2f(h4.w);
                *(float4*)&fout[(size_t)m * N + coln] = y;
            }
        }
        __syncthreads();
    }
}

// ---------------- final LayerNorm, wave-per-row, in-place.  grid 4096 x 256 --------------
__global__ __launch_bounds__(256) void k_final_ln(const float* __restrict__ ln_w,
                                                  const float* __restrict__ ln_b,
                                                  float* __restrict__ out) {
    int wave = threadIdx.x >> 6, lane = threadIdx.x & 63;
    size_t row = (size_t)blockIdx.x * 4 + wave;
    float4 v[4];
    float s = 0.f;
    #pragma unroll
    for (int q = 0; q < 4; ++q) {
        v[q] = *(const float4*)&out[row * H + q * 256 + lane * 4];
        s += v[q].x + v[q].y + v[q].z + v[q].w;
    }
    #pragma unroll
    for (int off = 1; off < 64; off <<= 1) s += __shfl_xor(s, off, 64);
    float mu = s * (1.0f / H);
    float ss = 0.f;
    #pragma unroll
    for (int q = 0; q < 4; ++q) {
        v[q].x -= mu; v[q].y -= mu; v[q].z -= mu; v[q].w -= mu;
        ss += v[q].x * v[q].x + v[q].y * v[q].y + v[q].z * v[q].z + v[q].w * v[q].w;
    }
    #pragma unroll
    for (int off = 1; off < 64; off <<= 1) ss += __shfl_xor(ss, off, 64);
    float rstd = rsqrtf(ss * (1.0f / H) + 1e-5f);
    #pragma unroll
    for (int q = 0; q < 4; ++q) {
        int k = q * 256 + lane * 4;
        float4 w4 = *(const float4*)&ln_w[k];
        float4 b4 = *(const float4*)&ln_b[k];
        float4 o;
        o.x = fmaf(v[q].x * rstd, w4.x, b4.x);
        o.y = fmaf(v[q].y * rstd, w4.y, b4.y);
        o.z = fmaf(v[q].z * rstd, w4.z, b4.z);
        o.w = fmaf(v[q].w * rstd, w4.w, b4.w);
        *(float4*)&out[row * H + k] = o;
    }
}

// ---------------- launch ----------------

extern "C" void kernel_launch(void* const* d_in, const int* in_sizes, int n_in,
                              void* d_out, int out_size, void* d_ws, size_t ws_size,
                              hipStream_t stream) {
    const float* h_time    = (const float*)d_in[0];
    const float* A_p       = (const float*)d_in[1];
    const float* E_dyn     = (const float*)d_in[2];
    const float* alpha_raw = (const float*)d_in[3];
    // d_in[4] = tau_raw: unused (softmax over axis 0 => node_attn.mean(0) == 1/N exactly)
    const float* gW1   = (const float*)d_in[5];
    const float* gb1   = (const float*)d_in[6];
    const float* gW2   = (const float*)d_in[7];
    const float* gb2   = (const float*)d_in[8];
    const float* h2n_W = (const float*)d_in[9];
    const float* h2n_b = (const float*)d_in[10];
    const float* n2h_W = (const float*)d_in[11];
    const float* n2h_b = (const float*)d_in[12];
    const float* ln_w  = (const float*)d_in[13];
    const float* ln_b  = (const float*)d_in[14];
    float* out = (float*)d_out;

    float* ws = (float*)d_ws;
    float* h_gate  = ws;  ws += Bb * H;
    float* h_mean  = ws;  ws += H;
    float* rowsumS = ws;  ws += Nn;
    float* bias_h  = ws;  ws += H;
    float* hid     = ws;  ws += Bb * 512;
    float* gmean   = ws;  ws += Nn;
    float* W1T     = ws;  ws += 512 * H;
    float* W2T     = ws;  ws += H * 512;
    float* hg_part = ws;  ws += 512 * H;       // 8 t-chunks x 64 b
    ws += 256;   // alignment pad
    ushort_t* E_b     = (ushort_t*)ws;  ws += (Nn * H) / 2;
    ushort_t* Sb      = (ushort_t*)ws;  ws += (Nn * Nn) / 2;
    ushort_t* AmixT_h = (ushort_t*)ws;  ws += (Nn * Nn) / 2;
    ushort_t* AmixT_l = (ushort_t*)ws;  ws += (Nn * Nn) / 2;
    ushort_t* n2hWT_h = (ushort_t*)ws;  ws += (Nn * H) / 2;
    ushort_t* n2hWT_l = (ushort_t*)ws;  ws += (Nn * H) / 2;
    ushort_t* h2nW_h  = (ushort_t*)ws;  ws += (H * Nn) / 2;
    ushort_t* h2nW_l  = (ushort_t*)ws;  ws += (H * Nn) / 2;
    ushort_t* C1Th    = (ushort_t*)ws;  ws += (H * Nn) / 2;
    ushort_t* C1Tl    = (ushort_t*)ws;  ws += (H * Nn) / 2;
    ushort_t* C2t     = (ushort_t*)ws;  ws += (H * H) / 2;
    ushort_t* ht      = (ushort_t*)ws;  ws += ((size_t)BT * H) / 2;

    // 1: hgate partials (x8 t-split) + bf16 ht + seeds + all weight prep
    k_stage1<<<5120, 256, 0, stream>>>(h_time, hg_part, ht, n2h_b, rowsumS, bias_h,
                                       n2h_W, h2n_W, gW1, gW2,
                                       n2hWT_h, n2hWT_l, h2nW_h, h2nW_l, W1T, W2T);
    // 2: h_gate + h_mean
    k_stage2<<<260, 256, 0, stream>>>(hg_part, h_gate, h_mean);
    // 3: E_cur bf16 + MLP layer 1
    k_stage3<<<9216, 256, 0, stream>>>(E_dyn, h_mean, E_b, h_gate, W1T, gb1, hid);
    // 4: MLP layer 2 (gmean) + S = relu(E E^T) bf16 + row sums
    k_stage4<<<512, 256, 0, stream>>>(hid, W2T, gb2, gmean, E_b, Sb, rowsumS);
    // 5: A_mix^T hi/lo
    k_amixT<<<dim3(32, 32), 256, 0, stream>>>(Sb, A_p, rowsumS, gmean, alpha_raw, AmixT_h, AmixT_l);
    // 6: C1T = n2h_W^T @ A_mix^T (3-pass) -> hi/lo + fused bias_h gemv
    k_c1t<<<256, 256, 0, stream>>>(n2hWT_h, n2hWT_l, AmixT_h, AmixT_l, C1Th, C1Tl, bias_h, h2n_b);
    // 7: C2t = C1T @ h2n_W (3-pass) -> bf16   (= C2^T, the big GEMM's B operand)
    k_c2t<<<256, 256, 0, stream>>>(C1Th, C1Tl, h2nW_h, h2nW_l, C2t);
    // 8: y = ht @ C2t^T + bias_h + SC*ht -> d_out fp32 (fused epilogue)
    gemm_big<<<256, 512, 0, stream>>>(ht, C2t, out, bias_h, BT, H, H);
    // 9: LayerNorm in place (wave per row)
    k_final_ln<<<4096, 256, 0, stream>>>(ln_w, ln_b, out);
}

// Round 4
// 316.418 us; speedup vs baseline: 1.0076x; 1.0076x over previous
//
#include <hip/hip_runtime.h>
#include <math.h>

#define H 1024
#define Nn 1024
#define Bb 64
#define Tt 256
#define BT (Bb * Tt)   // 16384

typedef unsigned short ushort_t;
typedef __attribute__((ext_vector_type(8))) short bf16x8;
typedef __attribute__((ext_vector_type(4))) float f32x4;

// ---------------- helpers ----------------

__device__ __forceinline__ ushort_t f2bf(float x) {
    union { float f; unsigned u; } v; v.f = x;
    unsigned r = v.u + 0x7FFFu + ((v.u >> 16) & 1u);   // RNE
    return (ushort_t)(r >> 16);
}
__device__ __forceinline__ float bf2f(ushort_t h) {
    union { unsigned u; float f; } v; v.u = ((unsigned)h) << 16; return v.f;
}

__device__ __forceinline__ float block_reduce_sum_256(float v) {
    __shared__ float sbuf[4];
    __syncthreads();
    #pragma unroll
    for (int off = 32; off > 0; off >>= 1) v += __shfl_down(v, off, 64);
    int lane = threadIdx.x & 63, w = threadIdx.x >> 6;
    if (lane == 0) sbuf[w] = v;
    __syncthreads();
    if (threadIdx.x == 0) sbuf[0] = sbuf[0] + sbuf[1] + sbuf[2] + sbuf[3];
    __syncthreads();
    return sbuf[0];
}

// ---------------- stage 1: hgate partials (t-split x8) + bf16 ht + seeds + weight prep ----
// grid 3584 x 256:
//  [0,512):     b = id>>3, z = id&7 (t-chunk of 32); thread handles 4 cols (float4/ushort4)
//  [512,1536):  n2h_W^T hi/lo bf16 transpose tiles
//  [1536,2560): h2n_W flat hi/lo split
//  [2560,3072): W1T fp32
//  [3072,3584): W2T fp32
__global__ void k_stage1(const float* __restrict__ h_time, float* __restrict__ hg_part,
                         ushort_t* __restrict__ ht_bf16, const float* __restrict__ n2h_b,
                         float* __restrict__ rowsumS, float* __restrict__ bias_h,
                         const float* __restrict__ n2h_W, const float* __restrict__ h2n_W,
                         const float* __restrict__ W1, const float* __restrict__ W2,
                         ushort_t* __restrict__ n2hWT_h, ushort_t* __restrict__ n2hWT_l,
                         ushort_t* __restrict__ h2nW_h, ushort_t* __restrict__ h2nW_l,
                         float* __restrict__ W1T, float* __restrict__ W2T) {
    __shared__ float tile[32][33];
    int id = blockIdx.x;
    if (id < 512) {
        int b = id >> 3, z = id & 7;
        int col = threadIdx.x * 4;
        if (b == 0 && z == 0) {        // seed atomic accumulators (ws re-poisoned every call)
            #pragma unroll
            for (int q = 0; q < 4; ++q) {
                rowsumS[col + q] = 0.f;
                bias_h[col + q] = n2h_b[col + q];
            }
        }
        float4 s4 = {0.f, 0.f, 0.f, 0.f};
        #pragma unroll 4
        for (int t = z * 32; t < z * 32 + 32; ++t) {
            size_t o = ((size_t)b * Tt + t) * H + col;
            float4 v = *(const float4*)&h_time[o];
            s4.x += v.x; s4.y += v.y; s4.z += v.z; s4.w += v.w;
            ushort4 h;
            h.x = f2bf(v.x); h.y = f2bf(v.y); h.z = f2bf(v.z); h.w = f2bf(v.w);
            *(ushort4*)&ht_bf16[o] = h;
        }
        *(float4*)&hg_part[(size_t)(b * 8 + z) * H + col] = s4;
        return;
    }
    int tx = threadIdx.x & 31, ty = threadIdx.x >> 5;
    if (id < 1536) {            // n2h_W transpose + split
        int t = id - 512;
        int i0 = (t >> 5) * 32, j0 = (t & 31) * 32;
        #pragma unroll
        for (int q = 0; q < 4; ++q)
            tile[ty + 8 * q][tx] = n2h_W[(size_t)(i0 + ty + 8 * q) * H + j0 + tx];
        __syncthreads();
        #pragma unroll
        for (int q = 0; q < 4; ++q) {
            float v = tile[tx][ty + 8 * q];
            size_t o = (size_t)(j0 + ty + 8 * q) * Nn + i0 + tx;
            ushort_t hh = f2bf(v);
            n2hWT_h[o] = hh;
            n2hWT_l[o] = f2bf(v - bf2f(hh));
        }
    } else if (id < 2560) {     // h2n_W flat split
        size_t idx = (size_t)(id - 1536) * 1024 + threadIdx.x * 4;
        float4 v = *(const float4*)&h2n_W[idx];
        float c[4] = {v.x, v.y, v.z, v.w};
        union { ushort_t u[4]; uint2 w; } ph, pl;
        #pragma unroll
        for (int q = 0; q < 4; ++q) {
            ph.u[q] = f2bf(c[q]);
            pl.u[q] = f2bf(c[q] - bf2f(ph.u[q]));
        }
        *(uint2*)&h2nW_h[idx] = ph.w;
        *(uint2*)&h2nW_l[idx] = pl.w;
    } else if (id < 3072) {     // W1T (W1 is 1024x512)
        int t = id - 2560;
        int i0 = (t >> 4) * 32, j0 = (t & 15) * 32;
        #pragma unroll
        for (int q = 0; q < 4; ++q)
            tile[ty + 8 * q][tx] = W1[(size_t)(i0 + ty + 8 * q) * 512 + j0 + tx];
        __syncthreads();
        #pragma unroll
        for (int q = 0; q < 4; ++q)
            W1T[(size_t)(j0 + ty + 8 * q) * 1024 + i0 + tx] = tile[tx][ty + 8 * q];
    } else {                    // W2T (W2 is 512x1024)
        int t = id - 3072;
        int i0 = (t >> 5) * 32, j0 = (t & 31) * 32;
        #pragma unroll
        for (int q = 0; q < 4; ++q)
            tile[ty + 8 * q][tx] = W2[(size_t)(i0 + ty + 8 * q) * 1024 + j0 + tx];
        __syncthreads();
        #pragma unroll
        for (int q = 0; q < 4; ++q)
            W2T[(size_t)(j0 + ty + 8 * q) * 512 + i0 + tx] = tile[tx][ty + 8 * q];
    }
}

// ---------------- stage 2: h_gate + h_mean from partials.  grid 260 x 256 ----------------
__global__ void k_stage2(const float* __restrict__ hg_part, float* __restrict__ h_gate,
                         float* __restrict__ h_mean) {
    int id = blockIdx.x;
    if (id < 256) {
        int b = id >> 2, cb = id & 3;
        int col = cb * 256 + threadIdx.x;
        float s = 0.f;
        #pragma unroll
        for (int z = 0; z < 8; ++z) s += hg_part[(size_t)(b * 8 + z) * H + col];
        h_gate[b * H + col] = s * (1.0f / Tt);
    } else {
        int h = (id - 256) * 256 + threadIdx.x;
        float s = 0.f;
        for (int r = 0; r < 512; ++r) s += hg_part[(size_t)r * H + h];
        h_mean[h] = s * (1.0f / (Bb * Tt));
    }
}

// ---------------- stage 3: E_cur bf16 + MLP layer 1.  grid 9216 x 256 --------------------
__global__ __launch_bounds__(256) void k_stage3(
    const float* __restrict__ E_dyn, const float* __restrict__ h_mean,
    ushort_t* __restrict__ E_b,
    const float* __restrict__ h_gate, const float* __restrict__ W1T,
    const float* __restrict__ b1, float* __restrict__ hid) {
    if (blockIdx.x < 1024) {   // E_b[n,:] = bf16(normalize(E_dyn[n,:] + h_mean))
        int n = blockIdx.x;
        float e[4]; float ss = 0.f;
        #pragma unroll
        for (int q = 0; q < 4; ++q) {
            int h = threadIdx.x + 256 * q;
            e[q] = E_dyn[(size_t)n * H + h] + h_mean[h];
            ss += e[q] * e[q];
        }
        float tot = block_reduce_sum_256(ss);
        float scale = 1.0f / fmaxf(sqrtf(tot), 1e-12f);
        #pragma unroll
        for (int q = 0; q < 4; ++q) {
            int h = threadIdx.x + 256 * q;
            E_b[(size_t)n * H + h] = f2bf(e[q] * scale);
        }
        return;
    }
    // hid[b][j] = gelu(dot(h_gate[b,:], W1T[j,:]) + b1[j]); wave per output
    int gid = (blockIdx.x - 1024) * 4 + (threadIdx.x >> 6);
    int lane = threadIdx.x & 63;
    int b = gid >> 9, j = gid & 511;
    const float* xr = h_gate + b * H;
    const float* wr = W1T + (size_t)j * H;
    float s = 0.f;
    #pragma unroll
    for (int it = 0; it < 4; ++it) {
        int k = it * 256 + lane * 4;
        float4 x4 = *(const float4*)&xr[k];
        float4 w4 = *(const float4*)&wr[k];
        s += x4.x * w4.x + x4.y * w4.y + x4.z * w4.z + x4.w * w4.w;
    }
    #pragma unroll
    for (int off = 32; off > 0; off >>= 1) s += __shfl_down(s, off, 64);
    if (lane == 0) {
        float a = s + b1[j];
        hid[b * 512 + j] = 0.5f * a * (1.0f + erff(a * 0.70710678118654752f));
    }
}

// ---------------- 64x64-tile MFMA GEMM body, BK=64, T2 swizzle + 2-phase pipeline --------
// C_raw = A@Bt^T (PASSES=1) or Ah@Bh^T + Ah@Bl^T + Al@Bh^T (PASSES=3).
// EPI 1: relu -> O1 bf16 + atomicAdd row-sums into fout.      (S = relu(E E^T))
// EPI 2: hi/lo bf16 -> O1,O2 + atomicAdd dot(row,fvec)->fout. (C1T + fused bias_h gemv)
// EPI 3: bf16 -> O1.                                          (C2t)
template <int PASSES, int EPI>
__device__ __forceinline__ void gemm64_body(
    int bx, int by,
    const ushort_t* __restrict__ Ah, const ushort_t* __restrict__ Al,
    const ushort_t* __restrict__ Bh, const ushort_t* __restrict__ Bl,
    ushort_t* __restrict__ O1, ushort_t* __restrict__ O2,
    float* __restrict__ fout, const float* __restrict__ fvec,
    int M, int N, int K) {
    constexpr int NST = (PASSES == 3) ? 4 : 2;
    constexpr int BUFSZ = NST * 64 * 64;
    __shared__ ushort_t sStage[2 * BUFSZ];   // double-buffered: 64 KB (3-pass) / 32 KB
    const int tid = threadIdx.x, wave = tid >> 6, lane = tid & 63;
    const int quad = lane >> 4, l16 = lane & 15;
    const int m0 = by * 64, n0 = bx * 64;
    const int wm = (wave >> 1) * 32, wn = (wave & 1) * 32;
    const int sw = (l16 & 7) << 3;   // read-side swizzle (row&7)<<3 in ushort units

    f32x4 acc[2][2];
    #pragma unroll
    for (int i = 0; i < 2; ++i)
        #pragma unroll
        for (int j = 0; j < 2; ++j)
            acc[i][j] = (f32x4){0.f, 0.f, 0.f, 0.f};

    auto stage = [&](int buf, int k0) {
        ushort_t* sAh = sStage + buf * BUFSZ;
        ushort_t* sBh = sAh + 64 * 64;
        ushort_t* sAl = sAh + 2 * 64 * 64;   // only used when PASSES==3
        ushort_t* sBl = sAh + 3 * 64 * 64;
        #pragma unroll
        for (int inst = 0; inst < 2; ++inst) {
            const int cbase = (wave * 2 + inst) * 64;
            const int c = cbase + lane;
            const int row = c >> 3;
            const int q = (c & 7) ^ (row & 7);   // inverse-swizzled source chunk
            const size_t offA = (size_t)(m0 + row) * K + k0 + q * 8;
            const size_t offB = (size_t)(n0 + row) * K + k0 + q * 8;
            __builtin_amdgcn_global_load_lds(
                (const __attribute__((address_space(1))) unsigned int*)(Ah + offA),
                (__attribute__((address_space(3))) unsigned int*)&sAh[cbase * 8], 16, 0, 0);
            __builtin_amdgcn_global_load_lds(
                (const __attribute__((address_space(1))) unsigned int*)(Bh + offB),
                (__attribute__((address_space(3))) unsigned int*)&sBh[cbase * 8], 16, 0, 0);
            if constexpr (PASSES == 3) {
                __builtin_amdgcn_global_load_lds(
                    (const __attribute__((address_space(1))) unsigned int*)(Al + offA),
                    (__attribute__((address_space(3))) unsigned int*)&sAl[cbase * 8], 16, 0, 0);
                __builtin_amdgcn_global_load_lds(
                    (const __attribute__((address_space(1))) unsigned int*)(Bl + offB),
                    (__attribute__((address_space(3))) unsigned int*)&sBl[cbase * 8], 16, 0, 0);
            }
        }
    };

    auto compute = [&](int buf) {
        const ushort_t* sAh = sStage + buf * BUFSZ;
        const ushort_t* sBh = sAh + 64 * 64;
        const ushort_t* sAl = sAh + 2 * 64 * 64;
        const ushort_t* sBl = sAh + 3 * 64 * 64;
        #pragma unroll
        for (int half = 0; half < 2; ++half) {
            bf16x8 fah[2], fbh[2];
            bf16x8 fal[PASSES == 3 ? 2 : 1], fbl[PASSES == 3 ? 2 : 1];
            #pragma unroll
            for (int i = 0; i < 2; ++i) {
                const int ko = ((half * 4 + quad) << 3) ^ sw;   // swizzled 16B chunk
                fah[i] = *(const bf16x8*)&sAh[(wm + i * 16 + l16) * 64 + ko];
                fbh[i] = *(const bf16x8*)&sBh[(wn + i * 16 + l16) * 64 + ko];
                if constexpr (PASSES == 3) {
                    fal[i] = *(const bf16x8*)&sAl[(wm + i * 16 + l16) * 64 + ko];
                    fbl[i] = *(const bf16x8*)&sBl[(wn + i * 16 + l16) * 64 + ko];
                }
            }
            #pragma unroll
            for (int i = 0; i < 2; ++i)
                #pragma unroll
                for (int j = 0; j < 2; ++j) {
                    acc[i][j] = __builtin_amdgcn_mfma_f32_16x16x32_bf16(fah[i], fbh[j], acc[i][j], 0, 0, 0);
                    if constexpr (PASSES == 3) {
                        acc[i][j] = __builtin_amdgcn_mfma_f32_16x16x32_bf16(fah[i], fbl[j], acc[i][j], 0, 0, 0);
                        acc[i][j] = __builtin_amdgcn_mfma_f32_16x16x32_bf16(fal[i], fbh[j], acc[i][j], 0, 0, 0);
                    }
                }
        }
    };

    // 2-phase pipelined K-loop
    stage(0, 0);
    __syncthreads();
    int cur = 0;
    for (int k0 = 64; k0 < K; k0 += 64) {
        stage(cur ^ 1, k0);   // next tile in flight across the compute
        compute(cur);
        __syncthreads();      // drains vmcnt(0): next buffer ready; reads done
        cur ^= 1;
    }
    compute(cur);

    // direct-from-register epilogue (outputs small/L2-resident; no LDS round-trip)
    float fv[2];
    if constexpr (EPI == 2) {
        #pragma unroll
        for (int j = 0; j < 2; ++j) fv[j] = fvec[n0 + wn + j * 16 + l16];
    }
    #pragma unroll
    for (int i = 0; i < 2; ++i)
        #pragma unroll
        for (int r = 0; r < 4; ++r) {
            const int m = m0 + wm + i * 16 + quad * 4 + r;
            float rowacc = 0.f;
            #pragma unroll
            for (int j = 0; j < 2; ++j) {
                const size_t o = (size_t)m * N + n0 + wn + j * 16 + l16;
                float v = acc[i][j][r];
                if constexpr (EPI == 1) {
                    v = fmaxf(v, 0.f);
                    O1[o] = f2bf(v);
                    rowacc += v;
                } else if constexpr (EPI == 2) {
                    ushort_t hh = f2bf(v);
                    O1[o] = hh;
                    O2[o] = f2bf(v - bf2f(hh));
                    rowacc += v * fv[j];
                } else {
                    O1[o] = f2bf(v);
                }
            }
            if constexpr (EPI == 1 || EPI == 2) {
                rowacc += __shfl_xor(rowacc, 1);
                rowacc += __shfl_xor(rowacc, 2);
                rowacc += __shfl_xor(rowacc, 4);
                rowacc += __shfl_xor(rowacc, 8);
                if (l16 == 0) atomicAdd(&fout[m], rowacc);
            }
        }
}

// ---------------- stage 4: MLP layer 2 (gmean) + S-GEMM.  grid 512 x 256 -----------------
__global__ __launch_bounds__(256) void k_stage4(
    const float* __restrict__ hid, const float* __restrict__ W2T,
    const float* __restrict__ b2, float* __restrict__ gmean,
    const ushort_t* __restrict__ E_b, ushort_t* __restrict__ Sb,
    float* __restrict__ rowsumS) {
    if (blockIdx.x < 256) {
        int n = blockIdx.x * 4 + (threadIdx.x >> 6);
        int lane = threadIdx.x & 63;
        const float* wr = W2T + (size_t)n * 512;
        float4 w0 = *(const float4*)&wr[lane * 4];
        float4 w1 = *(const float4*)&wr[256 + lane * 4];
        float bb = b2[n];
        float acc = 0.f;
        for (int b = 0; b < Bb; ++b) {
            const float* xr = hid + b * 512;
            float4 x0 = *(const float4*)&xr[lane * 4];
            float4 x1 = *(const float4*)&xr[256 + lane * 4];
            float s = x0.x * w0.x + x0.y * w0.y + x0.z * w0.z + x0.w * w0.w
                    + x1.x * w1.x + x1.y * w1.y + x1.z * w1.z + x1.w * w1.w;
            #pragma unroll
            for (int off = 32; off > 0; off >>= 1) s += __shfl_down(s, off, 64);
            if (lane == 0) acc += 1.0f / (1.0f + expf(-(s + bb)));
        }
        if (lane == 0) gmean[n] = acc * (1.0f / Bb);
        return;
    }
    int t = blockIdx.x - 256;
    gemm64_body<1, 1>(t & 15, t >> 4, E_b, nullptr, E_b, nullptr,
                      Sb, nullptr, rowsumS, nullptr, Nn, Nn, H);
}

// ---------------- A_mix transposed + hi/lo split.  grid(32,32) x 256 ---------------------
__global__ void k_amixT(const ushort_t* __restrict__ Sb, const float* __restrict__ A_p,
                        const float* __restrict__ rowsumS, const float* __restrict__ gmean,
                        const float* __restrict__ alpha_raw,
                        ushort_t* __restrict__ Th, ushort_t* __restrict__ Tl) {
    __shared__ float tile[32][33];
    int i0 = blockIdx.y * 32, j0 = blockIdx.x * 32;
    int tx = threadIdx.x & 31, ty = threadIdx.x >> 5;
    float alpha = 1.0f / (1.0f + expf(-alpha_raw[0]));
    #pragma unroll
    for (int q = 0; q < 4; ++q) {
        int i = i0 + ty + 8 * q, j = j0 + tx;
        size_t idx = (size_t)i * Nn + j;
        float s = bf2f(Sb[idx]);
        float ad = 0.5f * s * (1.0f / (rowsumS[i] + 1e-6f) + 1.0f / (rowsumS[j] + 1e-6f));
        tile[ty + 8 * q][tx] = gmean[i] * fmaf(alpha, A_p[idx], (1.0f - alpha) * ad);
    }
    __syncthreads();
    #pragma unroll
    for (int q = 0; q < 4; ++q) {
        float v = tile[tx][ty + 8 * q];
        size_t o = (size_t)(j0 + ty + 8 * q) * Nn + i0 + tx;
        ushort_t hh = f2bf(v);
        Th[o] = hh;
        Tl[o] = f2bf(v - bf2f(hh));
    }
}

// chain GEMM wrappers.  grid 256 x 256
__global__ __launch_bounds__(256) void k_c1t(
    const ushort_t* __restrict__ Ah, const ushort_t* __restrict__ Al,
    const ushort_t* __restrict__ Bh, const ushort_t* __restrict__ Bl,
    ushort_t* __restrict__ O1, ushort_t* __restrict__ O2,
    float* __restrict__ fout, const float* __restrict__ fvec) {
    gemm64_body<3, 2>(blockIdx.x & 15, blockIdx.x >> 4, Ah, Al, Bh, Bl, O1, O2, fout, fvec,
                      Nn, Nn, Nn);
}
__global__ __launch_bounds__(256) void k_c2t(
    const ushort_t* __restrict__ Ah, const ushort_t* __restrict__ Al,
    const ushort_t* __restrict__ Bh, const ushort_t* __restrict__ Bl,
    ushort_t* __restrict__ O1) {
    gemm64_body<3, 3>(blockIdx.x & 15, blockIdx.x >> 4, Ah, Al, Bh, Bl, O1, nullptr,
                      nullptr, nullptr, Nn, Nn, Nn);
}

// ---------------- 256x256 MFMA GEMM, BK=64, 8 waves, XCD-local mapping -------------------
// y[m][n] = (ht @ C2t^T)[m][n] + bias[n] + SC*bf16(ht[m][n]), fp32 -> fout.
// T1 (bijective XCD remap): xcd = bid&7 owns m-tiles [xcd*8, xcd*8+8); n-inner.  Each
// 512 KB A-panel lives on exactly ONE XCD's L2 (A fetched once from HBM); B is L3-served;
// the epilogue's A re-read hits the same L2.
// T2 swizzle: linear LDS dest, inverse-swizzled global source chunk, swizzled ds_read.
// Schedule: 2 phases per K-tile {half-stage issue; 12 ds_read; s_barrier; lgkmcnt(0);
// setprio(1); 32 MFMA; setprio(0); s_barrier}; single vmcnt drain per tile via
// __syncthreads() (only the tile issued a full tile ago is outstanding).
__global__ __launch_bounds__(512, 2) void gemm_big(
    const ushort_t* __restrict__ A, const ushort_t* __restrict__ Bt,
    float* __restrict__ fout, const float* __restrict__ fvec,
    int M, int N, int K) {
    constexpr int BUFSZ = 2 * 256 * 64;              // per-buffer ushorts (A+B)
    __shared__ ushort_t sStage[2 * BUFSZ];           // 128 KB

    const int tid = threadIdx.x;
    const int wave = tid >> 6, lane = tid & 63;
    const int quad = lane >> 4, l16 = lane & 15;
    const int wr = wave >> 2, wc = wave & 3;         // 2 x 4 wave grid
    const int xcd = blockIdx.x & 7, idx = blockIdx.x >> 3;
    const int m0 = (xcd * 8 + (idx >> 2)) * 256;     // 8 m-panels per XCD, n-inner
    const int n0 = (idx & 3) * 256;
    const int wm = wr * 128, wn = wc * 64;           // per-wave 128 x 64 output
    const int swz = l16 & 7;

    f32x4 acc[8][4];
    #pragma unroll
    for (int i = 0; i < 8; ++i)
        #pragma unroll
        for (int j = 0; j < 4; ++j)
            acc[i][j] = (f32x4){0.f, 0.f, 0.f, 0.f};

    auto stage_half = [&](int buf, int k0, int half) {
        ushort_t* sA = sStage + buf * BUFSZ;
        ushort_t* sB = sA + 256 * 64;
        #pragma unroll
        for (int pass = 0; pass < 2; ++pass) {
            const int c = (half * 2 + pass) * 512 + tid;
            const int row = c >> 3;
            const int q = (c & 7) ^ (row & 7);   // inverse-swizzled source chunk
            const size_t offA = (size_t)(m0 + row) * K + k0 + q * 8;
            const size_t offB = (size_t)(n0 + row) * K + k0 + q * 8;
            __builtin_amdgcn_global_load_lds(
                (const __attribute__((address_space(1))) unsigned int*)(A + offA),
                (__attribute__((address_space(3))) unsigned int*)&sA[c * 8], 16, 0, 0);
            __builtin_amdgcn_global_load_lds(
                (const __attribute__((address_space(1))) unsigned int*)(Bt + offB),
                (__attribute__((address_space(3))) unsigned int*)&sB[c * 8], 16, 0, 0);
        }
    };

    stage_half(0, 0, 0);
    stage_half(0, 0, 1);
    int buf = 0;
    for (int t = 0; t < 16; ++t) {
        __syncthreads();   // drain: only tile t's loads outstanding (issued one tile ago)
        const ushort_t* sA = sStage + buf * BUFSZ;
        const ushort_t* sB = sA + 256 * 64;
        #pragma unroll
        for (int s = 0; s < 2; ++s) {          // K-half: one phase of 32 MFMA
            if (t + 1 < 16) stage_half(buf ^ 1, (t + 1) * 64, s);   // spread next-tile stage
            bf16x8 fb[4], fa[8];
            const int ch = (s * 4 + quad) ^ swz;
            #pragma unroll
            for (int j = 0; j < 4; ++j)
                fb[j] = *(const bf16x8*)&sB[(wn + j * 16 + l16) * 64 + ch * 8];
            #pragma unroll
            for (int i = 0; i < 8; ++i)
                fa[i] = *(const bf16x8*)&sA[(wm + i * 16 + l16) * 64 + ch * 8];
            __builtin_amdgcn_s_barrier();
            asm volatile("s_waitcnt lgkmcnt(0)" ::: "memory");
            __builtin_amdgcn_sched_barrier(0);
            __builtin_amdgcn_s_setprio(1);
            #pragma unroll
            for (int i = 0; i < 8; ++i)
                #pragma unroll
                for (int j = 0; j < 4; ++j)
                    acc[i][j] = __builtin_amdgcn_mfma_f32_16x16x32_bf16(fa[i], fb[j], acc[i][j], 0, 0, 0);
            __builtin_amdgcn_s_setprio(0);
            __builtin_amdgcn_s_barrier();
        }
        buf ^= 1;
    }
    __syncthreads();   // staging dead; epilogue overlays the full 128 KB

    // Epilogue: per-wave LDS transpose (16 KB/wave = 4 m-frags per pass, 2 passes) ->
    // coalesced float4 IO.  __syncthreads between write/read: type-punned LDS (R4 lesson).
    float* Es = (float*)sStage + wave * 4096;
    const float SC = 1.0009765622f;   // 1 + tanh(1/1024): attention branch is this constant

    #pragma unroll
    for (int pass = 0; pass < 2; ++pass) {
        #pragma unroll
        for (int ii = 0; ii < 4; ++ii) {
            const int i = pass * 4 + ii;
            #pragma unroll
            for (int j = 0; j < 4; ++j)
                #pragma unroll
                for (int r = 0; r < 4; ++r)
                    Es[ii * 1024 + (quad * 4 + r) * 64 + j * 16 + l16] = acc[i][j][r];
        }
        __syncthreads();
        #pragma unroll
        for (int ii = 0; ii < 4; ++ii) {
            #pragma unroll
            for (int it = 0; it < 4; ++it) {
                const int idx2 = it * 64 + lane;
                const int row = idx2 >> 4, f4 = idx2 & 15;
                const int m = m0 + wm + (pass * 4 + ii) * 16 + row;
                const int coln = n0 + wn + f4 * 4;
                float4 v = *(const float4*)&Es[ii * 1024 + row * 64 + f4 * 4];
                float4 b4 = *(const float4*)&fvec[coln];
                ushort4 h4 = *(const ushort4*)&A[(size_t)m * N + coln];
                float4 y;
                y.x = v.x + b4.x + SC * bf2f(h4.x);
                y.y = v.y + b4.y + SC * bf2f(h4.y);
                y.z = v.z + b4.z + SC * bf2f(h4.z);
                y.w = v.w + b4.w + SC * bf2f(h4.w);
                *(float4*)&fout[(size_t)m * N + coln] = y;
            }
        }
        __syncthreads();
    }
}

// ---------------- final LayerNorm, wave-per-row, in-place.  grid 4096 x 256 --------------
__global__ __launch_bounds__(256) void k_final_ln(const float* __restrict__ ln_w,
                                                  const float* __restrict__ ln_b,
                                                  float* __restrict__ out) {
    int wave = threadIdx.x >> 6, lane = threadIdx.x & 63;
    size_t row = (size_t)blockIdx.x * 4 + wave;
    float4 v[4];
    float s = 0.f;
    #pragma unroll
    for (int q = 0; q < 4; ++q) {
        v[q] = *(const float4*)&out[row * H + q * 256 + lane * 4];
        s += v[q].x + v[q].y + v[q].z + v[q].w;
    }
    #pragma unroll
    for (int off = 1; off < 64; off <<= 1) s += __shfl_xor(s, off, 64);
    float mu = s * (1.0f / H);
    float ss = 0.f;
    #pragma unroll
    for (int q = 0; q < 4; ++q) {
        v[q].x -= mu; v[q].y -= mu; v[q].z -= mu; v[q].w -= mu;
        ss += v[q].x * v[q].x + v[q].y * v[q].y + v[q].z * v[q].z + v[q].w * v[q].w;
    }
    #pragma unroll
    for (int off = 1; off < 64; off <<= 1) ss += __shfl_xor(ss, off, 64);
    float rstd = rsqrtf(ss * (1.0f / H) + 1e-5f);
    #pragma unroll
    for (int q = 0; q < 4; ++q) {
        int k = q * 256 + lane * 4;
        float4 w4 = *(const float4*)&ln_w[k];
        float4 b4 = *(const float4*)&ln_b[k];
        float4 o;
        o.x = fmaf(v[q].x * rstd, w4.x, b4.x);
        o.y = fmaf(v[q].y * rstd, w4.y, b4.y);
        o.z = fmaf(v[q].z * rstd, w4.z, b4.z);
        o.w = fmaf(v[q].w * rstd, w4.w, b4.w);
        *(float4*)&out[row * H + k] = o;
    }
}

// ---------------- launch ----------------

extern "C" void kernel_launch(void* const* d_in, const int* in_sizes, int n_in,
                              void* d_out, int out_size, void* d_ws, size_t ws_size,
                              hipStream_t stream) {
    const float* h_time    = (const float*)d_in[0];
    const float* A_p       = (const float*)d_in[1];
    const float* E_dyn     = (const float*)d_in[2];
    const float* alpha_raw = (const float*)d_in[3];
    // d_in[4] = tau_raw: unused (softmax over axis 0 => node_attn.mean(0) == 1/N exactly)
    const float* gW1   = (const float*)d_in[5];
    const float* gb1   = (const float*)d_in[6];
    const float* gW2   = (const float*)d_in[7];
    const float* gb2   = (const float*)d_in[8];
    const float* h2n_W = (const float*)d_in[9];
    const float* h2n_b = (const float*)d_in[10];
    const float* n2h_W = (const float*)d_in[11];
    const float* n2h_b = (const float*)d_in[12];
    const float* ln_w  = (const float*)d_in[13];
    const float* ln_b  = (const float*)d_in[14];
    float* out = (float*)d_out;

    float* ws = (float*)d_ws;
    float* h_gate  = ws;  ws += Bb * H;
    float* h_mean  = ws;  ws += H;
    float* rowsumS = ws;  ws += Nn;
    float* bias_h  = ws;  ws += H;
    float* hid     = ws;  ws += Bb * 512;
    float* gmean   = ws;  ws += Nn;
    float* W1T     = ws;  ws += 512 * H;
    float* W2T     = ws;  ws += H * 512;
    float* hg_part = ws;  ws += 512 * H;       // 8 t-chunks x 64 b
    ws += 256;   // alignment pad
    ushort_t* E_b     = (ushort_t*)ws;  ws += (Nn * H) / 2;
    ushort_t* Sb      = (ushort_t*)ws;  ws += (Nn * Nn) / 2;
    ushort_t* AmixT_h = (ushort_t*)ws;  ws += (Nn * Nn) / 2;
    ushort_t* AmixT_l = (ushort_t*)ws;  ws += (Nn * Nn) / 2;
    ushort_t* n2hWT_h = (ushort_t*)ws;  ws += (Nn * H) / 2;
    ushort_t* n2hWT_l = (ushort_t*)ws;  ws += (Nn * H) / 2;
    ushort_t* h2nW_h  = (ushort_t*)ws;  ws += (H * Nn) / 2;
    ushort_t* h2nW_l  = (ushort_t*)ws;  ws += (H * Nn) / 2;
    ushort_t* C1Th    = (ushort_t*)ws;  ws += (H * Nn) / 2;
    ushort_t* C1Tl    = (ushort_t*)ws;  ws += (H * Nn) / 2;
    ushort_t* C2t     = (ushort_t*)ws;  ws += (H * H) / 2;
    ushort_t* ht      = (ushort_t*)ws;  ws += ((size_t)BT * H) / 2;

    // 1: hgate partials (x8 t-split) + bf16 ht + seeds + all weight prep
    k_stage1<<<3584, 256, 0, stream>>>(h_time, hg_part, ht, n2h_b, rowsumS, bias_h,
                                       n2h_W, h2n_W, gW1, gW2,
                                       n2hWT_h, n2hWT_l, h2nW_h, h2nW_l, W1T, W2T);
    // 2: h_gate + h_mean
    k_stage2<<<260, 256, 0, stream>>>(hg_part, h_gate, h_mean);
    // 3: E_cur bf16 + MLP layer 1
    k_stage3<<<9216, 256, 0, stream>>>(E_dyn, h_mean, E_b, h_gate, W1T, gb1, hid);
    // 4: MLP layer 2 (gmean) + S = relu(E E^T) bf16 + row sums
    k_stage4<<<512, 256, 0, stream>>>(hid, W2T, gb2, gmean, E_b, Sb, rowsumS);
    // 5: A_mix^T hi/lo
    k_amixT<<<dim3(32, 32), 256, 0, stream>>>(Sb, A_p, rowsumS, gmean, alpha_raw, AmixT_h, AmixT_l);
    // 6: C1T = n2h_W^T @ A_mix^T (3-pass) -> hi/lo + fused bias_h gemv
    k_c1t<<<256, 256, 0, stream>>>(n2hWT_h, n2hWT_l, AmixT_h, AmixT_l, C1Th, C1Tl, bias_h, h2n_b);
    // 7: C2t = C1T @ h2n_W (3-pass) -> bf16   (= C2^T, the big GEMM's B operand)
    k_c2t<<<256, 256, 0, stream>>>(C1Th, C1Tl, h2nW_h, h2nW_l, C2t);
    // 8: y = ht @ C2t^T + bias_h + SC*ht -> d_out fp32 (fused epilogue)
    gemm_big<<<256, 512, 0, stream>>>(ht, C2t, out, bias_h, BT, H, H);
    // 9: LayerNorm in place (wave per row)
    k_final_ln<<<4096, 256, 0, stream>>>(ln_w, ln_b, out);
}